// Round 13
// baseline (129.475 us; speedup 1.0000x reference)
//
#include <hip/hip_runtime.h>
#include <hip/hip_bf16.h>
#include <hip/hip_fp16.h>
#include <math.h>

#define M_ROWS 16384
#define DIM 1024

typedef __attribute__((ext_vector_type(8))) short short8;
typedef __attribute__((ext_vector_type(4))) float f32x4;

#define MFMA_BF16(a, b, c) __builtin_amdgcn_mfma_f32_16x16x32_bf16(a, b, c, 0, 0, 0)

#define GLOAD16(gp, lp) __builtin_amdgcn_global_load_lds( \
    (const __attribute__((address_space(1))) unsigned int*)(gp), \
    (__attribute__((address_space(3))) unsigned int*)(lp), 16, 0, 0)

__device__ __forceinline__ short bf16_hi(float x) {
    return (short)__bfloat16_as_ushort(__float2bfloat16(x));
}

__device__ __forceinline__ float fast_asinh(float x) {
    float ax = fabsf(x);
    float r = __logf(ax + sqrtf(fmaf(ax, ax, 1.0f)));
    return copysignf(r, x);
}
__device__ __forceinline__ float fast_sinh(float x) {
    float e = __expf(x), em = __expf(-x);
    return 0.5f * (e - em);
}

__device__ __forceinline__ float waveReduceSum(float v) {
#pragma unroll
    for (int off = 32; off > 0; off >>= 1) v += __shfl_down(v, off, 64);
    return v;
}

// ---- column norms of weigh_v (axis=0) ----
__global__ void colnorm_partial(const float* __restrict__ W, float* __restrict__ part) {
    int col = (blockIdx.x & 3) * 256 + threadIdx.x;
    int r0 = (blockIdx.x >> 2) * 128;
    float s = 0.f;
#pragma unroll 8
    for (int i = 0; i < 128; ++i) {
        float t = W[(size_t)(r0 + i) * DIM + col];
        s += t * t;
    }
    part[(size_t)(blockIdx.x >> 2) * DIM + col] = s;
}

__global__ void colnorm_final(const float* __restrict__ part, float* __restrict__ invn) {
    int col = blockIdx.x * 256 + threadIdx.x;
    float s = 0.f;
#pragma unroll
    for (int p = 0; p < 8; ++p) s += part[(size_t)p * DIM + col];
    float n = fminf(fmaxf(sqrtf(s), 1e-6f), 1e6f);
    invn[col] = 1.0f / n;
}

// ---- transpose weigh_v to bf16: Bws[n][k] row-major ----
__global__ __launch_bounds__(256) void wtrans(const float* __restrict__ W,
                                              short* __restrict__ Bws) {
    __shared__ float tile[64][65];
    const int t = threadIdx.x;
    const int k0 = (blockIdx.x >> 4) * 64, n0 = (blockIdx.x & 15) * 64;
    const int rk = t >> 4;          // 0..15
    const int cn = (t & 15) * 4;    // 0..60
#pragma unroll
    for (int p = 0; p < 4; ++p) {
        float4 v = *(const float4*)&W[(size_t)(k0 + rk + p * 16) * DIM + n0 + cn];
        tile[rk + p * 16][cn + 0] = v.x;
        tile[rk + p * 16][cn + 1] = v.y;
        tile[rk + p * 16][cn + 2] = v.z;
        tile[rk + p * 16][cn + 3] = v.w;
    }
    __syncthreads();
    const int rn = t >> 4;
    const int ck = (t & 15) * 4;
#pragma unroll
    for (int p = 0; p < 4; ++p) {
        int n = rn + p * 16;
        union { short s[4]; uint2 u; } ph;
#pragma unroll
        for (int e = 0; e < 4; ++e) ph.s[e] = bf16_hi(tile[ck + e][n]);
        *(uint2*)&Bws[(size_t)(n0 + n) * DIM + k0 + ck] = ph.u;
    }
}

// ---- per-row prep: rowscale factor, cx2, bf16 cast: Aws[row][k] ----
__global__ __launch_bounds__(256) void rowprep_bf16(
    const float* __restrict__ in, const float* __restrict__ cptr,
    short* __restrict__ Aws, float* __restrict__ cx2) {
    const int row = blockIdx.x, t = threadIdx.x;
    float4 v = ((const float4*)(in + (size_t)row * DIM))[t];
    float s = v.x * v.x + v.y * v.y + v.z * v.z + v.w * v.w;
    s = waveReduceSum(s);
    __shared__ float red[4];
    __shared__ float rsv_sh;
    int wid = t >> 6, lane = t & 63;
    if (lane == 0) red[wid] = s;
    __syncthreads();
    if (t == 0) {
        float stot = red[0] + red[1] + red[2] + red[3];
        float cc = cptr[0], rc = sqrtf(cc);
        float un = sqrtf(fmaxf(stot, 1e-15f));          // _safe_norm(u)
        float xs = tanhf(rc * un) / (rc * un);          // x = xs*u
        float xn = sqrtf(fmaxf(xs * xs * stot, 1e-15f));
        float mn = (1.0f - 1e-5f) / rc;
        float pf = (xn > mn) ? (mn / xn) : 1.0f;        // proj
        float rsv = rc * xs * pf;                       // rcx = rsv*u
        rsv_sh = rsv;
        cx2[row] = rsv * rsv * stot;
    }
    __syncthreads();
    float rsv = rsv_sh;
    union { short s[4]; uint2 u; } ph;
    ph.s[0] = bf16_hi(v.x * rsv);
    ph.s[1] = bf16_hi(v.y * rsv);
    ph.s[2] = bf16_hi(v.z * rsv);
    ph.s[3] = bf16_hi(v.w * rsv);
    *(uint2*)&Aws[(size_t)row * DIM + t * 4] = ph.u;
}

// ---- MFMA GEMM (single-product bf16), 256x256 tile, 8 waves (2M x 4N) ----
// BK=64, 16 steps, FULL UNROLL. A ring-3 (96 KB) + B ring-2 (64 KB) = 160 KB.
// Depth-2 A prefetch / depth-1 B prefetch, counted per-wave vmcnt(4) (issue
// order B(s+1) then A(s+2) -> oldest-drain leaves A(s+2) in flight). One
// barrier per step (publish + WAR fence). Wave-owned staging as round 12.
// Output y written fp16 to Yh (halves finalize traffic).
__global__ __launch_bounds__(512, 2) void gemm_mfma(
    const short* __restrict__ Aws, const short* __restrict__ Bws,
    const float* __restrict__ cx2, const float* __restrict__ invn,
    const float* __restrict__ wg, const float* __restrict__ bias,
    const float* __restrict__ cptr, unsigned short* __restrict__ Yh) {
    __shared__ char smem[163840];   // A ring-3 @0 (3x32K), B ring-2 @98304 (2x32K)

    // 256 blocks = 64 by x 4 bx; XCD-chunked swizzle (256 % 8 == 0, bijective)
    const int j = blockIdx.x;
    const int wgid = (j & 7) * 32 + (j >> 3);
    const int by = wgid >> 2, bx = wgid & 3;
    const int row0 = by * 256, col0 = bx * 256;

    const int t = threadIdx.x;              // 0..511
    const int l = t & 63, w = t >> 6;       // 8 waves
    const int wr = (w >> 2) * 128, wc = (w & 3) * 64;
    const int fr = l & 15, fk3 = l >> 4;

    // read-side swizzled slot offsets (shorts)
    const int swl = fr >> 1;
    const int pk0 = (fk3 ^ swl) * 8;
    const int pk1 = ((4 | fk3) ^ swl) * 8;

    // ---- wave-ownership staging geometry (verified round 12) ----
    const int arow0 = (w >> 2) * 128 + (w & 3) * 32;   // my 32 A-rows
    const int brow0 = (w & 3) * 64 + (w >> 2) * 32;    // my 32 B-rows
    const int lrow8 = l >> 3;
    const int se = ((l & 7) ^ (l >> 4)) * 8;           // source slot, g even
    const int so = ((l & 7) ^ (4 | (l >> 4))) * 8;     // g odd
    const size_t gA_base = (size_t)(row0 + arow0 + lrow8) * DIM;
    const size_t gB_base = (size_t)(col0 + brow0 + lrow8) * DIM;
    const int dAoff = arow0 * 64 + l * 8;              // shorts (+ g*512)
    const int dBoff = brow0 * 64 + l * 8;

#define STAGEA(dst, kb) do { \
        GLOAD16(Aws + gA_base +     0 + (kb) + se, (dst) + dAoff);        \
        GLOAD16(Aws + gA_base +  8192 + (kb) + so, (dst) + dAoff + 512);  \
        GLOAD16(Aws + gA_base + 16384 + (kb) + se, (dst) + dAoff + 1024); \
        GLOAD16(Aws + gA_base + 24576 + (kb) + so, (dst) + dAoff + 1536); \
    } while (0)
#define STAGEB(dst, kb) do { \
        GLOAD16(Bws + gB_base +     0 + (kb) + se, (dst) + dBoff);        \
        GLOAD16(Bws + gB_base +  8192 + (kb) + so, (dst) + dBoff + 512);  \
        GLOAD16(Bws + gB_base + 16384 + (kb) + se, (dst) + dBoff + 1024); \
        GLOAD16(Bws + gB_base + 24576 + (kb) + so, (dst) + dBoff + 1536); \
    } while (0)

    f32x4 acc[8][4] = {};

    // prologue: B(0)->bbuf0, A(0)->abuf0, A(1)->abuf1
    STAGEB((short*)(smem + 98304), 0);
    STAGEA((short*)smem, 0);
    STAGEA((short*)(smem + 32768), 64);
    asm volatile("s_waitcnt vmcnt(0)" ::: "memory");

#pragma unroll
    for (int s = 0; s < 16; ++s) {
        const short* sA = (const short*)(smem + (s % 3) * 32768);
        const short* sB = (const short*)(smem + 98304 + (s & 1) * 32768);

        // publish buf s (everyone drained own loads before arriving);
        // also WAR fence for the buffers staged below
        __builtin_amdgcn_s_barrier();
        asm volatile("" ::: "memory");

        if (s < 15) STAGEB((short*)(smem + 98304 + ((s + 1) & 1) * 32768),
                           (size_t)(s + 1) * 64);
        if (s < 14) STAGEA((short*)(smem + ((s + 2) % 3) * 32768),
                           (size_t)(s + 2) * 64);

        short8 af[8], bq[4];
        // ---- kc0 ----
#pragma unroll
        for (int n = 0; n < 4; ++n)
            bq[n] = *(const short8*)&sB[(wc + n * 16 + fr) * 64 + pk0];
#pragma unroll
        for (int ig = 0; ig < 8; ++ig)
            af[ig] = *(const short8*)&sA[(wr + ig * 16 + fr) * 64 + pk0];
        __builtin_amdgcn_s_setprio(1);
#pragma unroll
        for (int ig = 0; ig < 8; ++ig)
#pragma unroll
            for (int n = 0; n < 4; ++n)
                acc[ig][n] = MFMA_BF16(af[ig], bq[n], acc[ig][n]);
        __builtin_amdgcn_s_setprio(0);
        // ---- kc1 ----
#pragma unroll
        for (int n = 0; n < 4; ++n)
            bq[n] = *(const short8*)&sB[(wc + n * 16 + fr) * 64 + pk1];
#pragma unroll
        for (int ig = 0; ig < 8; ++ig)
            af[ig] = *(const short8*)&sA[(wr + ig * 16 + fr) * 64 + pk1];
        __builtin_amdgcn_s_setprio(1);
#pragma unroll
        for (int ig = 0; ig < 8; ++ig)
#pragma unroll
            for (int n = 0; n < 4; ++n)
                acc[ig][n] = MFMA_BF16(af[ig], bq[n], acc[ig][n]);
        __builtin_amdgcn_s_setprio(0);

        // counted drain: oldest 8 = {A(s+1),B(s+1)} must land for next step;
        // newest 4 = A(s+2) stay in flight. Tail: drain all.
        if (s < 14) asm volatile("s_waitcnt vmcnt(4)" ::: "memory");
        else        asm volatile("s_waitcnt vmcnt(0)" ::: "memory");
    }
#undef STAGEA
#undef STAGEB

    // all staging drained; make every wave's last ds_reads complete before
    // slabs overwrite the B-ring region
    __builtin_amdgcn_s_barrier();

    // ---- epilogue: math in fragment layout, per-wave LDS slab -> fp16 ----
    const float cv = cptr[0];
    const float rcv = sqrtf(cv);
    const float inv_rc = 1.0f / rcv;
    const int fc = l & 15, fq = (l >> 4) * 4;

    float chf[4], shf[4], wff[4];
#pragma unroll
    for (int n = 0; n < 4; ++n) {
        const int col = col0 + wc + n * 16 + fc;
        float dr = 2.0f * rcv * bias[col];
        chf[n] = coshf(dr) * 2.0f * invn[col];   // folds 2*invn
        shf[n] = sinhf(dr);
        wff[n] = 2.0f * wg[col] * inv_rc;
    }

    // per-wave PRIVATE slab (in B-ring region): 16x64 f32, stride 68, 4.25 KB
    float* slab = (float*)(smem + 98304 + w * 8192);
    const int rr = l >> 4;          // 0..3
    const int rc16 = l & 15;        // 0..15

#pragma unroll
    for (int i = 0; i < 8; ++i) {
        float cxr[4];
#pragma unroll
        for (int q = 0; q < 4; ++q)
            cxr[q] = cx2[row0 + wr + i * 16 + fq + q];
#pragma unroll
        for (int n = 0; n < 4; ++n)
#pragma unroll
            for (int q = 0; q < 4; ++q) {
                float a = acc[i][n][q];
                float mlr = fmaf(a, chf[n], -(1.0f + cxr[q]) * shf[n]);
                float wv = wff[n] * fast_asinh(mlr);
                slab[(fq + q) * 68 + n * 16 + fc] = fast_sinh(rcv * wv) * inv_rc;
            }
#pragma unroll
        for (int p = 0; p < 4; ++p) {
            float4 v4 = *(const float4*)&slab[(p * 4 + rr) * 68 + rc16 * 4];
            union { unsigned short us[4]; uint2 u; } ho;
            ho.us[0] = __half_as_ushort(__float2half(v4.x));
            ho.us[1] = __half_as_ushort(__float2half(v4.y));
            ho.us[2] = __half_as_ushort(__float2half(v4.z));
            ho.us[3] = __half_as_ushort(__float2half(v4.w));
            *(uint2*)&Yh[(size_t)(row0 + wr + i * 16 + p * 4 + rr) * DIM +
                         col0 + wc + rc16 * 4] = ho.u;
        }
    }
}

// ---- per-row finalize (fp16 in, fp32 out): denom + relu-tangent + logmap0 ----
__global__ void finalize_h(const unsigned short* __restrict__ Yh,
                           float* __restrict__ out,
                           const float* __restrict__ cptr) {
    int row = blockIdx.x;
    const ushort4 hv = ((const ushort4*)(Yh + (size_t)row * DIM))[threadIdx.x];
    float y0 = __half2float(__ushort_as_half(hv.x));
    float y1 = __half2float(__ushort_as_half(hv.y));
    float y2 = __half2float(__ushort_as_half(hv.z));
    float y3 = __half2float(__ushort_as_half(hv.w));
    float s1 = y0 * y0 + y1 * y1 + y2 * y2 + y3 * y3;
    float rx = fmaxf(y0, 0.f), ryy = fmaxf(y1, 0.f);
    float rz = fmaxf(y2, 0.f), rw = fmaxf(y3, 0.f);
    float s2 = rx * rx + ryy * ryy + rz * rz + rw * rw;
    s1 = waveReduceSum(s1);
    s2 = waveReduceSum(s2);
    __shared__ float red1[4], red2[4];
    int wid = threadIdx.x >> 6, lane = threadIdx.x & 63;
    if (lane == 0) { red1[wid] = s1; red2[wid] = s2; }
    __syncthreads();
    s1 = red1[0] + red1[1] + red1[2] + red1[3];
    s2 = red2[0] + red2[1] + red2[2] + red2[3];

    const float c = cptr[0];
    const float rc = sqrtf(c);
    float g = 1.0f / (1.0f + sqrtf(1.0f + c * s1));     // x = g*y
    float xn = sqrtf(fmaxf(g * g * s1, 1e-15f));
    float arg = fminf(rc * xn, 1.0f - 1e-7f);
    float f1 = atanhf(arg) / (rc * xn);                  // u = f1*x
    float fv = f1 * g;                                   // v = fv*relu(y)
    float vn = sqrtf(fmaxf(fv * fv * s2, 1e-15f));
    float f2 = tanhf(rc * vn) / (rc * vn);               // e = f2*v
    float en = sqrtf(fmaxf(f2 * f2 * fv * fv * s2, 1e-15f));
    float maxnorm = (1.0f - 1e-5f) / rc;
    float pf = (en > maxnorm) ? (maxnorm / en) : 1.0f;   // z = pf*e
    float zn = sqrtf(fmaxf(pf * pf * f2 * f2 * fv * fv * s2, 1e-15f));
    float arg2 = fminf(rc * zn, 1.0f - 1e-7f);
    float f3 = atanhf(arg2) / (rc * zn);                 // out = f3*z
    float F = f3 * pf * f2 * fv;

    ((float4*)(out + (size_t)row * DIM))[threadIdx.x] =
        make_float4(F * rx, F * ryy, F * rz, F * rw);
}

extern "C" void kernel_launch(void* const* d_in, const int* in_sizes, int n_in,
                              void* d_out, int out_size, void* d_ws, size_t ws_size,
                              hipStream_t stream) {
    const float* inputs   = (const float*)d_in[0];
    const float* weigh_v  = (const float*)d_in[1];
    const float* weight_g = (const float*)d_in[2];
    const float* bias     = (const float*)d_in[3];
    const float* cptr     = (const float*)d_in[4];
    float* out = (float*)d_out;

    // workspace layout (~66.3 MB)
    char* ws = (char*)d_ws;
    short* Aws = (short*)ws;                                       // 32 MB
    short* Bws = (short*)(ws + (size_t)32 * 1024 * 1024);          // 2 MB
    unsigned short* Yh = (unsigned short*)(ws + (size_t)34 * 1024 * 1024); // 32 MB
    float* invn    = (float*)(ws + (size_t)66 * 1024 * 1024);      // 4 KB
    float* cx2     = (float*)(ws + (size_t)66 * 1024 * 1024 + 65536);    // 64 KB
    float* colpart = (float*)(ws + (size_t)66 * 1024 * 1024 + 131072);   // 32 KB

    colnorm_partial<<<32, 256, 0, stream>>>(weigh_v, colpart);
    colnorm_final<<<4, 256, 0, stream>>>(colpart, invn);
    wtrans<<<256, 256, 0, stream>>>(weigh_v, Bws);
    rowprep_bf16<<<M_ROWS, 256, 0, stream>>>(inputs, cptr, Aws, cx2);

    gemm_mfma<<<256, 512, 0, stream>>>(Aws, Bws, cx2, invn,
                                       weight_g, bias, cptr, Yh);

    finalize_h<<<M_ROWS, 256, 0, stream>>>(Yh, out, cptr);
}

// Round 17
// 127.905 us; speedup vs baseline: 1.0123x; 1.0123x over previous
//
#include <hip/hip_runtime.h>
#include <hip/hip_bf16.h>
#include <hip/hip_fp16.h>
#include <math.h>

#define M_ROWS 16384
#define DIM 1024

typedef __attribute__((ext_vector_type(8))) short short8;
typedef __attribute__((ext_vector_type(4))) float f32x4;

#define MFMA_BF16(a, b, c) __builtin_amdgcn_mfma_f32_16x16x32_bf16(a, b, c, 0, 0, 0)

#define GLOAD16(gp, lp) __builtin_amdgcn_global_load_lds( \
    (const __attribute__((address_space(1))) unsigned int*)(gp), \
    (__attribute__((address_space(3))) unsigned int*)(lp), 16, 0, 0)

__device__ __forceinline__ short bf16_hi(float x) {
    return (short)__bfloat16_as_ushort(__float2bfloat16(x));
}

__device__ __forceinline__ float fast_asinh(float x) {
    float ax = fabsf(x);
    float r = __logf(ax + sqrtf(fmaf(ax, ax, 1.0f)));
    return copysignf(r, x);
}
__device__ __forceinline__ float fast_sinh(float x) {
    float e = __expf(x), em = __expf(-x);
    return 0.5f * (e - em);
}

__device__ __forceinline__ float waveReduceSum(float v) {
#pragma unroll
    for (int off = 32; off > 0; off >>= 1) v += __shfl_down(v, off, 64);
    return v;
}

// ---- fused: transpose W to bf16 Bws[n][k] + per-k-block column norm partials ----
// part[kblk][col], kblk = k0/64 (16), col (1024)
__global__ __launch_bounds__(256) void wtrans_colnorm(const float* __restrict__ W,
                                                      short* __restrict__ Bws,
                                                      float* __restrict__ part) {
    __shared__ float tile[64][65];
    __shared__ float cred[4][64];
    const int t = threadIdx.x;
    const int k0 = (blockIdx.x >> 4) * 64, n0 = (blockIdx.x & 15) * 64;
    const int rk = t >> 4;          // 0..15
    const int cn = (t & 15) * 4;    // 0..60
#pragma unroll
    for (int p = 0; p < 4; ++p) {
        float4 v = *(const float4*)&W[(size_t)(k0 + rk + p * 16) * DIM + n0 + cn];
        tile[rk + p * 16][cn + 0] = v.x;
        tile[rk + p * 16][cn + 1] = v.y;
        tile[rk + p * 16][cn + 2] = v.z;
        tile[rk + p * 16][cn + 3] = v.w;
    }
    __syncthreads();
    // column sum-of-squares partials (column = local n, over 64 local k)
    {
        const int c = t & 63, q = t >> 6;
        float s = 0.f;
#pragma unroll
        for (int i = 0; i < 16; ++i) {
            float v = tile[q * 16 + i][c];
            s = fmaf(v, v, s);
        }
        cred[q][c] = s;
    }
    const int rn = t >> 4;
    const int ck = (t & 15) * 4;
#pragma unroll
    for (int p = 0; p < 4; ++p) {
        int n = rn + p * 16;
        union { short s[4]; uint2 u; } ph;
#pragma unroll
        for (int e = 0; e < 4; ++e) ph.s[e] = bf16_hi(tile[ck + e][n]);
        *(uint2*)&Bws[(size_t)(n0 + n) * DIM + k0 + ck] = ph.u;
    }
    __syncthreads();
    if (t < 64)
        part[(size_t)(blockIdx.x >> 4) * 1024 + n0 + t] =
            cred[0][t] + cred[1][t] + cred[2][t] + cred[3][t];
}

// ---- per-row prep (rowscale, cx2, bf16 cast) + tail blocks do colnorm final ----
__global__ __launch_bounds__(256) void rowprep_bf16(
    const float* __restrict__ in, const float* __restrict__ cptr,
    short* __restrict__ Aws, float* __restrict__ cx2,
    const float* __restrict__ part, float* __restrict__ invn) {
    const int t = threadIdx.x;
    if (blockIdx.x >= M_ROWS) {     // colnorm final: 4 tail blocks
        int col = (blockIdx.x - M_ROWS) * 256 + t;
        float s = 0.f;
#pragma unroll
        for (int p = 0; p < 16; ++p) s += part[(size_t)p * 1024 + col];
        float n = fminf(fmaxf(sqrtf(s), 1e-6f), 1e6f);
        invn[col] = 1.0f / n;
        return;
    }
    const int row = blockIdx.x;
    float4 v = ((const float4*)(in + (size_t)row * DIM))[t];
    float s = v.x * v.x + v.y * v.y + v.z * v.z + v.w * v.w;
    s = waveReduceSum(s);
    __shared__ float red[4];
    __shared__ float rsv_sh;
    int wid = t >> 6, lane = t & 63;
    if (lane == 0) red[wid] = s;
    __syncthreads();
    if (t == 0) {
        float stot = red[0] + red[1] + red[2] + red[3];
        float cc = cptr[0], rc = sqrtf(cc);
        float un = sqrtf(fmaxf(stot, 1e-15f));          // _safe_norm(u)
        float xs = tanhf(rc * un) / (rc * un);          // x = xs*u
        float xn = sqrtf(fmaxf(xs * xs * stot, 1e-15f));
        float mn = (1.0f - 1e-5f) / rc;
        float pf = (xn > mn) ? (mn / xn) : 1.0f;        // proj
        float rsv = rc * xs * pf;                       // rcx = rsv*u
        rsv_sh = rsv;
        cx2[row] = rsv * rsv * stot;
    }
    __syncthreads();
    float rsv = rsv_sh;
    union { short sgn[4]; uint2 u; } ph;
    ph.sgn[0] = bf16_hi(v.x * rsv);
    ph.sgn[1] = bf16_hi(v.y * rsv);
    ph.sgn[2] = bf16_hi(v.z * rsv);
    ph.sgn[3] = bf16_hi(v.w * rsv);
    *(uint2*)&Aws[(size_t)row * DIM + t * 4] = ph.u;
}

// ---- MFMA GEMM (single-product bf16), 128x256 tile, 4 waves (64x128 each) ----
// BK=32 (64B LDS rows, 4 slots), 32 steps, full unroll. A ring-3 (24 KB) +
// B ring-2 (32 KB) = 56 KB -> 2 blocks/CU (cross-block wave overlap hides
// barrier/drain stalls). Counted vmcnt(2): end-of-step drains {A(s+1),B(s+1)},
// leaves A(s+2) in flight. Swizzle: slot' = slot ^ (r&3) ^ ((r>>2)&3).
// Wave-owned staging: A rows w*32..+31 (2 gloads), B rows w*64..+63 (4).
__global__ __launch_bounds__(256, 2) void gemm_mfma(
    const short* __restrict__ Aws, const short* __restrict__ Bws,
    const float* __restrict__ cx2, const float* __restrict__ invn,
    const float* __restrict__ wg, const float* __restrict__ bias,
    const float* __restrict__ cptr, unsigned short* __restrict__ Yh) {
    __shared__ char smem[57344];    // A ring-3 @0 (3x8K), B ring-2 @24576 (2x16K)

    // 512 blocks = 128 by x 4 bx; XCD-chunked swizzle (512 % 8 == 0, bijective)
    const int j = blockIdx.x;
    const int wgid = (j & 7) * 64 + (j >> 3);
    const int by = wgid >> 2, bx = wgid & 3;
    const int row0 = by * 128, col0 = bx * 256;

    const int t = threadIdx.x;              // 0..255
    const int l = t & 63, w = t >> 6;       // 4 waves
    const int wr = (w & 1) * 64, wc = (w >> 1) * 128;
    const int fr = l & 15, fk3 = l >> 4;    // 0..3

    // read-side swizzled slot offset (shorts)
    const int pk = (fk3 ^ (fr & 3) ^ ((fr >> 2) & 3)) * 8;
    // staging source pre-swizzle (row_t = l>>2, slot_t = l&3)
    const int se = (((l & 3) ^ ((l >> 2) & 3) ^ ((l >> 4) & 3))) * 8;

    const size_t gA_r = (size_t)(row0 + w * 32 + (l >> 2)) * DIM + se;
    const size_t gB_r = (size_t)(col0 + w * 64 + (l >> 2)) * DIM + se;
    short* const dA0 = (short*)smem;        // + ring*4096 shorts
    short* const dB0 = (short*)(smem + 24576);

#define STAGEA(ring, s) do { \
        short* d_ = dA0 + (ring) * 4096 + w * 1024; \
        GLOAD16(Aws + gA_r + (size_t)(s) * 32,         d_);       \
        GLOAD16(Aws + gA_r + (size_t)(s) * 32 + 16384, d_ + 512); \
    } while (0)
#define STAGEB(ring, s) do { \
        short* d_ = dB0 + (ring) * 8192 + w * 2048; \
        GLOAD16(Bws + gB_r + (size_t)(s) * 32,         d_);        \
        GLOAD16(Bws + gB_r + (size_t)(s) * 32 + 16384, d_ + 512);  \
        GLOAD16(Bws + gB_r + (size_t)(s) * 32 + 32768, d_ + 1024); \
        GLOAD16(Bws + gB_r + (size_t)(s) * 32 + 49152, d_ + 1536); \
    } while (0)

    f32x4 acc[4][8] = {};

    // prologue: B(0)->bbuf0, A(0)->abuf0, A(1)->abuf1; drain all
    STAGEB(0, 0);
    STAGEA(0, 0);
    STAGEA(1, 1);
    asm volatile("s_waitcnt vmcnt(0)" ::: "memory");

#pragma unroll
    for (int s = 0; s < 32; ++s) {
        const short* sA = (const short*)(dA0 + (s % 3) * 4096);
        const short* sB = (const short*)(dB0 + (s & 1) * 8192);

        // step-top barrier: publishes buf s; WAR fence for buffers staged below
        __builtin_amdgcn_s_barrier();
        asm volatile("" ::: "memory");

        if (s < 31) STAGEB((s + 1) & 1, s + 1);
        if (s < 30) STAGEA((s + 2) % 3, s + 2);

        short8 af[4], bq[8];
#pragma unroll
        for (int n = 0; n < 8; ++n)
            bq[n] = *(const short8*)&sB[(wc + n * 16 + fr) * 32 + pk];
#pragma unroll
        for (int ig = 0; ig < 4; ++ig)
            af[ig] = *(const short8*)&sA[(wr + ig * 16 + fr) * 32 + pk];

        __builtin_amdgcn_s_setprio(1);
#pragma unroll
        for (int ig = 0; ig < 4; ++ig)
#pragma unroll
            for (int n = 0; n < 8; ++n)
                acc[ig][n] = MFMA_BF16(af[ig], bq[n], acc[ig][n]);
        __builtin_amdgcn_s_setprio(0);

        if (s < 30) asm volatile("s_waitcnt vmcnt(2)" ::: "memory");
        else        asm volatile("s_waitcnt vmcnt(0)" ::: "memory");
    }
#undef STAGEA
#undef STAGEB

    __builtin_amdgcn_s_barrier();   // rings dead; slabs may reuse LDS

    // ---- epilogue: math in fragment layout, per-wave LDS slab -> fp16 ----
    const float cv = cptr[0];
    const float rcv = sqrtf(cv);
    const float inv_rc = 1.0f / rcv;
    const int fc = l & 15, fq = (l >> 4) * 4;

    float chf[8], shf[8], wff[8];
#pragma unroll
    for (int n = 0; n < 8; ++n) {
        const int col = col0 + wc + n * 16 + fc;
        float dr = 2.0f * rcv * bias[col];
        chf[n] = coshf(dr) * 2.0f * invn[col];   // folds 2*invn
        shf[n] = sinhf(dr);
        wff[n] = 2.0f * wg[col] * inv_rc;
    }

    // per-wave PRIVATE slab: 16 rows x 128 cols f32, stride 132 (8448 B)
    float* slab = (float*)(smem + w * 8448);
    const int rr2 = l >> 5;          // 0..1 (store-phase row within pair)
    const int c32 = (l & 31) * 4;    // 0..124

#pragma unroll
    for (int ig = 0; ig < 4; ++ig) {
        float cxr[4];
#pragma unroll
        for (int q = 0; q < 4; ++q)
            cxr[q] = cx2[row0 + wr + ig * 16 + fq + q];
#pragma unroll
        for (int n = 0; n < 8; ++n)
#pragma unroll
            for (int q = 0; q < 4; ++q) {
                float a = acc[ig][n][q];
                float mlr = fmaf(a, chf[n], -(1.0f + cxr[q]) * shf[n]);
                float wv = wff[n] * fast_asinh(mlr);
                slab[(fq + q) * 132 + n * 16 + fc] = fast_sinh(rcv * wv) * inv_rc;
            }
        // slab private to wave: lgkm ordering within wave suffices
#pragma unroll
        for (int p = 0; p < 8; ++p) {
            int r = p * 2 + rr2;
            float4 v4 = *(const float4*)&slab[r * 132 + c32];
            union { unsigned short us[4]; uint2 u; } ho;
            ho.us[0] = __half_as_ushort(__float2half(v4.x));
            ho.us[1] = __half_as_ushort(__float2half(v4.y));
            ho.us[2] = __half_as_ushort(__float2half(v4.z));
            ho.us[3] = __half_as_ushort(__float2half(v4.w));
            *(uint2*)&Yh[(size_t)(row0 + wr + ig * 16 + r) * DIM +
                         col0 + wc + c32] = ho.u;
        }
    }
}

// ---- per-row finalize (fp16 in, fp32 out): denom + relu-tangent + logmap0 ----
__global__ void finalize_h(const unsigned short* __restrict__ Yh,
                           float* __restrict__ out,
                           const float* __restrict__ cptr) {
    int row = blockIdx.x;
    const ushort4 hv = ((const ushort4*)(Yh + (size_t)row * DIM))[threadIdx.x];
    float y0 = __half2float(__ushort_as_half(hv.x));
    float y1 = __half2float(__ushort_as_half(hv.y));
    float y2 = __half2float(__ushort_as_half(hv.z));
    float y3 = __half2float(__ushort_as_half(hv.w));
    float s1 = y0 * y0 + y1 * y1 + y2 * y2 + y3 * y3;
    float rx = fmaxf(y0, 0.f), ryy = fmaxf(y1, 0.f);
    float rz = fmaxf(y2, 0.f), rw = fmaxf(y3, 0.f);
    float s2 = rx * rx + ryy * ryy + rz * rz + rw * rw;
    s1 = waveReduceSum(s1);
    s2 = waveReduceSum(s2);
    __shared__ float red1[4], red2[4];
    int wid = threadIdx.x >> 6, lane = threadIdx.x & 63;
    if (lane == 0) { red1[wid] = s1; red2[wid] = s2; }
    __syncthreads();
    s1 = red1[0] + red1[1] + red1[2] + red1[3];
    s2 = red2[0] + red2[1] + red2[2] + red2[3];

    const float c = cptr[0];
    const float rc = sqrtf(c);
    float g = 1.0f / (1.0f + sqrtf(1.0f + c * s1));     // x = g*y
    float xn = sqrtf(fmaxf(g * g * s1, 1e-15f));
    float arg = fminf(rc * xn, 1.0f - 1e-7f);
    float f1 = atanhf(arg) / (rc * xn);                  // u = f1*x
    float fv = f1 * g;                                   // v = fv*relu(y)
    float vn = sqrtf(fmaxf(fv * fv * s2, 1e-15f));
    float f2 = tanhf(rc * vn) / (rc * vn);               // e = f2*v
    float en = sqrtf(fmaxf(f2 * f2 * fv * fv * s2, 1e-15f));
    float maxnorm = (1.0f - 1e-5f) / rc;
    float pf = (en > maxnorm) ? (maxnorm / en) : 1.0f;   // z = pf*e
    float zn = sqrtf(fmaxf(pf * pf * f2 * f2 * fv * fv * s2, 1e-15f));
    float arg2 = fminf(rc * zn, 1.0f - 1e-7f);
    float f3 = atanhf(arg2) / (rc * zn);                 // out = f3*z
    float F = f3 * pf * f2 * fv;

    ((float4*)(out + (size_t)row * DIM))[threadIdx.x] =
        make_float4(F * rx, F * ryy, F * rz, F * rw);
}

extern "C" void kernel_launch(void* const* d_in, const int* in_sizes, int n_in,
                              void* d_out, int out_size, void* d_ws, size_t ws_size,
                              hipStream_t stream) {
    const float* inputs   = (const float*)d_in[0];
    const float* weigh_v  = (const float*)d_in[1];
    const float* weight_g = (const float*)d_in[2];
    const float* bias     = (const float*)d_in[3];
    const float* cptr     = (const float*)d_in[4];
    float* out = (float*)d_out;

    // workspace layout (~66.3 MB)
    char* ws = (char*)d_ws;
    short* Aws = (short*)ws;                                       // 32 MB
    short* Bws = (short*)(ws + (size_t)32 * 1024 * 1024);          // 2 MB
    unsigned short* Yh = (unsigned short*)(ws + (size_t)34 * 1024 * 1024); // 32 MB
    float* invn = (float*)(ws + (size_t)66 * 1024 * 1024);         // 4 KB
    float* cx2  = (float*)(ws + (size_t)66 * 1024 * 1024 + 65536); // 64 KB
    float* part = (float*)(ws + (size_t)66 * 1024 * 1024 + 131072);// 64 KB (16x1024)

    wtrans_colnorm<<<256, 256, 0, stream>>>(weigh_v, Bws, part);
    rowprep_bf16<<<M_ROWS + 4, 256, 0, stream>>>(inputs, cptr, Aws, cx2,
                                                 part, invn);
    gemm_mfma<<<512, 256, 0, stream>>>(Aws, Bws, cx2, invn,
                                       weight_g, bias, cptr, Yh);
    finalize_h<<<M_ROWS, 256, 0, stream>>>(Yh, out, cptr);
}